// Round 9
// baseline (534.081 us; speedup 1.0000x reference)
//
#include <hip/hip_runtime.h>
#include <hip/hip_bf16.h>

// Problem constants (static per reference)
#define NTOK 16384   // B*T
#define HD   512     // H
#define ED   8       // E experts
#define FD   2048    // F
#define CAP  5120    // capacity per expert
#define NA   32768   // NTOK * K(=2)

typedef __bf16 bf16x8 __attribute__((ext_vector_type(8)));
typedef float  f32x4  __attribute__((ext_vector_type(4)));

// Workspace layout (bytes). Total ~218 MB.
static constexpr size_t OFF_EIDX = 0;                                  // int[NA]
static constexpr size_t OFF_WGT  = 131072;                             // float[NA]
static constexpr size_t OFF_STOK = 262144;                             // int[ED*CAP]
static constexpr size_t OFF_SWGT = 458752;                             // float[ED*CAP]
static constexpr size_t OFF_W2T  = 1u << 20;                           // bf16[ED][HD][FD]
static constexpr size_t OFF_H    = OFF_W2T + (size_t)ED*HD*FD*2;       // bf16[ED][CAP][FD]
static constexpr size_t OFF_W1T  = OFF_H   + (size_t)ED*CAP*FD*2;      // bf16[ED][FD][HD]
static constexpr size_t OFF_XBF  = OFF_W1T + (size_t)ED*FD*HD*2;       // bf16[NTOK][HD]

__device__ __forceinline__ unsigned short f2bf(float f) {
    __bf16 b = (__bf16)f;
    return __builtin_bit_cast(unsigned short, b);
}

// gelu(tanh approx) == v * sigmoid(2*0.79788456*(v + 0.044715 v^3))  (exact identity)
__device__ __forceinline__ float gelu_fast(float v) {
    const float u = 1.5957691216057308f * (v + 0.044715f * v * v * v);
    return v / (1.f + __expf(-u));
}

// ---------------------------------------------------------------------------
// in: [R][C] fp32 (per expert)  ->  out: [C][R] bf16 (per expert)
// ---------------------------------------------------------------------------
__global__ __launch_bounds__(256) void transpose_cast_kernel(
    const float* __restrict__ in, unsigned short* __restrict__ out, int R, int C)
{
    __shared__ unsigned short tile[32][33];
    const int e = blockIdx.z;
    in  += (size_t)e * R * C;
    out += (size_t)e * R * C;
    const int r0 = blockIdx.y * 32, c0 = blockIdx.x * 32;
    const int tr = threadIdx.x >> 3, tc = (threadIdx.x & 7) * 4;
    const float4 v = *(const float4*)(in + (size_t)(r0 + tr) * C + c0 + tc);
    tile[tr][tc + 0] = f2bf(v.x);
    tile[tr][tc + 1] = f2bf(v.y);
    tile[tr][tc + 2] = f2bf(v.z);
    tile[tr][tc + 3] = f2bf(v.w);
    __syncthreads();
    ushort4 o;
    o.x = tile[tc + 0][tr]; o.y = tile[tc + 1][tr];
    o.z = tile[tc + 2][tr]; o.w = tile[tc + 3][tr];
    *(ushort4*)(out + (size_t)(c0 + tr) * R + r0 + tc) = o;
}

// ---------------------------------------------------------------------------
// Router (+ fused x->bf16 cast + out zeroing): logits = x @ rw, top-2, softmax.
// ---------------------------------------------------------------------------
__global__ __launch_bounds__(256) void router_kernel(
    const float* __restrict__ x, const float* __restrict__ rw,
    int* __restrict__ eidx, float* __restrict__ wgt,
    unsigned short* __restrict__ xbf, float* __restrict__ outz)
{
    __shared__ float rws[HD * ED];
    const int tid = threadIdx.x;
    for (int i = tid * 4; i < HD * ED; i += 256 * 4)
        *(float4*)(rws + i) = *(const float4*)(rw + i);
    __syncthreads();

    const int wid = tid >> 6, lane = tid & 63;
    const int t = blockIdx.x * 4 + wid;
    const float* xr = x + (size_t)t * HD;

    // zero the output row (atomic-combine target; harness poisons d_out)
    const float4 z = make_float4(0.f, 0.f, 0.f, 0.f);
    *(float4*)(outz + (size_t)t * HD + lane * 8)     = z;
    *(float4*)(outz + (size_t)t * HD + lane * 8 + 4) = z;

    float acc[ED];
#pragma unroll
    for (int e = 0; e < ED; e++) acc[e] = 0.f;

    float4 xv0 = *(const float4*)(xr + lane * 8);
    float4 xv1 = *(const float4*)(xr + lane * 8 + 4);
    float xv[8] = {xv0.x, xv0.y, xv0.z, xv0.w, xv1.x, xv1.y, xv1.z, xv1.w};

    union { unsigned short us[8]; uint4 v; } pk;
#pragma unroll
    for (int j = 0; j < 8; j++) pk.us[j] = f2bf(xv[j]);
    *(uint4*)(xbf + (size_t)t * HD + lane * 8) = pk.v;

#pragma unroll
    for (int j = 0; j < 8; j++) {
        const int h = lane * 8 + j;
#pragma unroll
        for (int e = 0; e < ED; e++) acc[e] += xv[j] * rws[h * ED + e];
    }
#pragma unroll
    for (int off = 32; off >= 1; off >>= 1) {
#pragma unroll
        for (int e = 0; e < ED; e++) acc[e] += __shfl_down(acc[e], off);
    }
    if (lane == 0) {
        int e0 = 0; float l0 = acc[0];
        for (int e = 1; e < ED; e++) if (acc[e] > l0) { l0 = acc[e]; e0 = e; }
        int e1 = 0; float l1 = -1e30f;
        for (int e = 0; e < ED; e++) {
            if (e == e0) continue;
            if (acc[e] > l1) { l1 = acc[e]; e1 = e; }
        }
        const float ex = expf(l1 - l0);
        const float inv = 1.f / (1.f + ex);
        eidx[t * 2 + 0] = e0;  eidx[t * 2 + 1] = e1;
        wgt [t * 2 + 0] = inv; wgt [t * 2 + 1] = ex * inv;
    }
}

// ---------------------------------------------------------------------------
// Deterministic slot assignment (stable-sort-by-expert), 3-phase / 2 barriers:
//  P1: per-(chunk,wave,expert) ballot counts -> LDS (no cross-wave deps)
//  P2: thread e serially prefix-sums 32x16 counts (chunk-major, wave-minor)
//  P3: re-ballot rank + offset -> stok/swgt (no cross deps)
// ---------------------------------------------------------------------------
__global__ __launch_bounds__(1024) void scan_kernel(
    const int* __restrict__ eidx, const float* __restrict__ wgt,
    int* __restrict__ stok, float* __restrict__ swgt)
{
    __shared__ int wcnt[32][16][ED];   // 16 KB; after P2 holds offsets
    const int tid = threadIdx.x;
    const int lane = tid & 63, wid = tid >> 6;
    const unsigned long long below = (1ull << lane) - 1ull;

    for (int i = tid; i < ED * CAP; i += 1024) stok[i] = -1;

    // P1: counts
    for (int c = 0; c < NA / 1024; c++) {
        const int e = eidx[c * 1024 + tid];
#pragma unroll
        for (int ee = 0; ee < ED; ee++) {
            unsigned long long m = __ballot(e == ee);
            if (lane == 0) wcnt[c][wid][ee] = __popcll(m);
        }
    }
    __syncthreads();

    // P2: per-expert serial prefix (512 adds by 8 threads)
    if (tid < ED) {
        int run = 0;
        for (int c = 0; c < 32; c++)
            for (int w = 0; w < 16; w++) {
                const int v = wcnt[c][w][tid];
                wcnt[c][w][tid] = run;
                run += v;
            }
    }
    __syncthreads();

    // P3: emit
    for (int c = 0; c < NA / 1024; c++) {
        const int a = c * 1024 + tid;
        const int e = eidx[a];
        int myrank = 0;
#pragma unroll
        for (int ee = 0; ee < ED; ee++) {
            unsigned long long m = __ballot(e == ee);
            if (ee == e) myrank = __popcll(m & below);
        }
        const int slot = wcnt[c][wid][e] + myrank;
        if (slot < CAP) {
            stok[e * CAP + slot] = a >> 1;   // token = a / K
            swgt[e * CAP + slot] = wgt[a];
        }
    }
}

// ---------------------------------------------------------------------------
// MFMA GEMM: 128x128 tile, BK=32, VGPR-staged single-barrier pipeline.
// R9 = R8's coalesced global staging (lanes 0..3 cover one row's 64 B -> 16
// cache lines per wave-op) + the PROVEN conflict-free LDS layout
// [kchunk(4)][row(128)][8] (uniform 8 words/bank per wave-op; R2-R7 showed 0
// conflicts, R8's padded layout showed 2.1e7).
// Pipeline: loads issued one iteration ahead of their ds_write; ONE barrier
// per K-step (lgkm only — no vmcnt drain since no global_load_lds).
// Mapping: id%8 == expert == XCD; n fastest -> gathered A rows L2-resident.
// FUSE=false: hout = gelu(A@B + bias) [bf16]. FUSE=true: atomic combine.
// ---------------------------------------------------------------------------
template<int KD, int ND, int NT, bool FUSE>
__global__ __launch_bounds__(256) void gemm_mfma(
    const unsigned short* __restrict__ Abase,
    const unsigned short* __restrict__ Bt,
    const float* __restrict__ bias,
    const int* __restrict__ stok,
    const float* __restrict__ swgt,
    unsigned short* __restrict__ hout,
    float* __restrict__ out)
{
    constexpr int BUFE = 4096;   // elements per buf per matrix (8 KB)
    __shared__ __align__(16) unsigned short As[2 * BUFE];
    __shared__ __align__(16) unsigned short Bs[2 * BUFE];

    const int tid = threadIdx.x;
    const int e  = blockIdx.x & 7;          // expert == XCD (id%8 round-robin)
    const int g  = blockIdx.x >> 3;
    const int n0 = (g % NT) * 128;          // n fastest: reuse gathered A rows in L2
    const int m0 = (g / NT) * 128;

    // Coalesced staging: thread covers rows r1, r1+64; 16B k-chunk q
    const int q  = tid & 3;
    const int r1 = tid >> 2;                // 0..63
    const int r2 = r1 + 64;

    size_t ai1, ai2;
    if (!FUSE) {
        const int t1 = stok[e * CAP + m0 + r1];
        const int t2 = stok[e * CAP + m0 + r2];
        ai1 = (size_t)(t1 >= 0 ? t1 : 0);   // dropped -> row 0 (weight 0 kills it)
        ai2 = (size_t)(t2 >= 0 ? t2 : 0);
    } else {
        ai1 = (size_t)(e * CAP + m0 + r1);
        ai2 = (size_t)(e * CAP + m0 + r2);
    }
    const unsigned short* arow1 = Abase + ai1 * KD + q * 8;
    const unsigned short* arow2 = Abase + ai2 * KD + q * 8;
    const unsigned short* brow1 = Bt + ((size_t)e * ND + n0 + r1) * KD + q * 8;
    const unsigned short* brow2 = Bt + ((size_t)e * ND + n0 + r2) * KD + q * 8;

    // ds_write elem offsets: [kchunk q][row][8]
    const int oW1 = (q * 128 + r1) * 8;
    const int oW2 = (q * 128 + r2) * 8;

    const int lane = tid & 63;
    const int wid  = tid >> 6;
    const int wrow = (wid & 1) * 64;
    const int wcol = (wid >> 1) * 64;
    const int l15  = lane & 15;
    const int quad = lane >> 4;
    const int foff = quad * 128 + l15;      // fragment base (bf16x8 units)

    f32x4 acc[4][4];
#pragma unroll
    for (int i = 0; i < 4; i++)
#pragma unroll
        for (int j = 0; j < 4; j++) acc[i][j] = (f32x4)0.f;

    // Prologue: tile 0 -> regs -> buf0; tile 1 -> regs
    float4 ra1 = *(const float4*)(arow1);
    float4 ra2 = *(const float4*)(arow2);
    float4 rb1 = *(const float4*)(brow1);
    float4 rb2 = *(const float4*)(brow2);
    *(float4*)(&As[oW1]) = ra1;
    *(float4*)(&As[oW2]) = ra2;
    *(float4*)(&Bs[oW1]) = rb1;
    *(float4*)(&Bs[oW2]) = rb2;
    if (32 < KD) {
        ra1 = *(const float4*)(arow1 + 32);
        ra2 = *(const float4*)(arow2 + 32);
        rb1 = *(const float4*)(brow1 + 32);
        rb2 = *(const float4*)(brow2 + 32);
    }
    __syncthreads();

#define COMPUTE(PBUF)                                                          \
    {                                                                          \
        const bf16x8* Av = (const bf16x8*)(As + (PBUF) * BUFE);                \
        const bf16x8* Bv = (const bf16x8*)(Bs + (PBUF) * BUFE);                \
        bf16x8 af[4], bfv[4];                                                  \
        _Pragma("unroll")                                                      \
        for (int i = 0; i < 4; i++) af[i]  = Av[foff + wrow + i * 16];         \
        _Pragma("unroll")                                                      \
        for (int j = 0; j < 4; j++) bfv[j] = Bv[foff + wcol + j * 16];         \
        _Pragma("unroll")                                                      \
        for (int i = 0; i < 4; i++)                                            \
            _Pragma("unroll")                                                  \
            for (int j = 0; j < 4; j++)                                        \
                acc[i][j] = __builtin_amdgcn_mfma_f32_16x16x32_bf16(           \
                    af[i], bfv[j], acc[i][j], 0, 0, 0);                        \
    }

    int rbuf = 0;
    for (int kc = 0; kc < KD; kc += 32) {
        const int wb = (rbuf ^ 1) * BUFE;
        if (kc + 32 < KD) {
            // ds_write tile kc+32 (vmcnt wait: loads issued one iteration ago)
            *(float4*)(&As[wb + oW1]) = ra1;
            *(float4*)(&As[wb + oW2]) = ra2;
            *(float4*)(&Bs[wb + oW1]) = rb1;
            *(float4*)(&Bs[wb + oW2]) = rb2;
            if (kc + 64 < KD) {
                ra1 = *(const float4*)(arow1 + kc + 64);
                ra2 = *(const float4*)(arow2 + kc + 64);
                rb1 = *(const float4*)(brow1 + kc + 64);
                rb2 = *(const float4*)(brow2 + kc + 64);
            }
        }
        COMPUTE(rbuf);
        __syncthreads();   // lgkm only — no vmcnt drain
        rbuf ^= 1;
    }
#undef COMPUTE

    // Epilogue. C/D layout: col = lane&15, row = quad*4 + reg.
    if (!FUSE) {
#pragma unroll
        for (int i = 0; i < 4; i++) {
#pragma unroll
            for (int g2 = 0; g2 < 4; g2++) {
                const int m = wrow + i * 16 + quad * 4 + g2;
                unsigned short* hrow = hout + ((size_t)e * CAP + m0 + m) * FD + n0;
#pragma unroll
                for (int j = 0; j < 4; j++) {
                    const int n = wcol + j * 16 + l15;
                    const float v = acc[i][j][g2] + bias[(size_t)e * ND + n0 + n];
                    hrow[n] = f2bf(gelu_fast(v));
                }
            }
        }
    } else {
#pragma unroll
        for (int i = 0; i < 4; i++) {
#pragma unroll
            for (int g2 = 0; g2 < 4; g2++) {
                const int m = wrow + i * 16 + quad * 4 + g2;
                const int tok = stok[e * CAP + m0 + m];
                if (tok >= 0) {
                    const float w = swgt[e * CAP + m0 + m];
                    float* orow = out + (size_t)tok * HD + n0;
#pragma unroll
                    for (int j = 0; j < 4; j++) {
                        const int n = wcol + j * 16 + l15;
                        const float v = (acc[i][j][g2] + bias[(size_t)e * ND + n0 + n]) * w;
                        atomicAdd(orow + n, v);
                    }
                }
            }
        }
    }
}

extern "C" void kernel_launch(void* const* d_in, const int* in_sizes, int n_in,
                              void* d_out, int out_size, void* d_ws, size_t ws_size,
                              hipStream_t stream)
{
    const float* x  = (const float*)d_in[0];
    const float* rw = (const float*)d_in[1];
    const float* w1 = (const float*)d_in[2];
    const float* b1 = (const float*)d_in[3];
    const float* w2 = (const float*)d_in[4];
    const float* b2 = (const float*)d_in[5];
    float* out = (float*)d_out;

    char* ws = (char*)d_ws;
    int*   eidx = (int*)  (ws + OFF_EIDX);
    float* wgt  = (float*)(ws + OFF_WGT);
    int*   stok = (int*)  (ws + OFF_STOK);
    float* swgt = (float*)(ws + OFF_SWGT);
    unsigned short* w2t  = (unsigned short*)(ws + OFF_W2T);
    unsigned short* hbuf = (unsigned short*)(ws + OFF_H);
    unsigned short* w1t  = (unsigned short*)(ws + OFF_W1T);
    unsigned short* xbf  = (unsigned short*)(ws + OFF_XBF);

    transpose_cast_kernel<<<dim3(FD / 32, HD / 32, ED), 256, 0, stream>>>(w1, w1t, HD, FD);
    transpose_cast_kernel<<<dim3(HD / 32, FD / 32, ED), 256, 0, stream>>>(w2, w2t, FD, HD);
    router_kernel<<<NTOK / 4, 256, 0, stream>>>(x, rw, eidx, wgt, xbf, out);
    scan_kernel<<<1, 1024, 0, stream>>>(eidx, wgt, stok, swgt);

    // GEMM1: h = gelu(gather(x) @ w1 + b1)  [bf16]
    gemm_mfma<HD, FD, FD/128, false>
        <<<8 * (FD/128) * (CAP/128), 256, 0, stream>>>(
        xbf, w1t, b1, stok, nullptr, hbuf, nullptr);

    // GEMM2 + fused combine: out[tok] += (h @ w2 + b2) * weight
    gemm_mfma<FD, HD, HD/128, true>
        <<<8 * (HD/128) * (CAP/128), 256, 0, stream>>>(
        hbuf, w2t, b2, stok, swgt, nullptr, out);
}